// Round 9
// baseline (83.437 us; speedup 1.0000x reference)
//
#include <hip/hip_runtime.h>

constexpr int M_ROWS = 16000;   // B*T
constexpr int DIM    = 512;
constexpr int NEXP   = 10;
constexpr int NSH    = 5;
constexpr int KTOP   = 5;

constexpr int TMA = 64;         // rows per gemm block
constexpr int NCB = 128;        // cols per gemm block (4 col-blocks)
constexpr int BK  = 32;         // k-tile
constexpr int NT  = DIM / BK;   // 16

constexpr int TMF = 32;         // rows per finalize block

typedef __attribute__((ext_vector_type(8))) short  bf16x8;
typedef __attribute__((ext_vector_type(4))) float  f32x4;

#define SB         __builtin_amdgcn_sched_barrier(0)
#define WAITVM(N)  do { asm volatile("s_waitcnt vmcnt(" #N ")" ::: "memory"); SB; } while (0)
#define BAR        do { __builtin_amdgcn_s_barrier(); SB; } while (0)

__device__ inline unsigned short bf16_rne(float x) {
    unsigned u = __float_as_uint(x);
    u += 0x7fffu + ((u >> 16) & 1u);
    return (unsigned short)(u >> 16);
}
__device__ inline float bf16_to_f(unsigned short h) {
    return __uint_as_float(((unsigned)h) << 16);
}

// ---------------- prep: W1 -> (hi,lo) bf16 [N][K]; shsum = sum_s shared_w ----
__global__ __launch_bounds__(256)
void prep_kernel(const float* __restrict__ W1, const float* __restrict__ shared_w,
                 unsigned short* __restrict__ w1hi, unsigned short* __restrict__ w1lo,
                 float* __restrict__ shsum)
{
    int b = blockIdx.x;
    if (b < 256) {
        int f = b * 256 + threadIdx.x;
        float4 v = *reinterpret_cast<const float4*>(&W1[(size_t)f * 4]);
        float xs[4] = {v.x, v.y, v.z, v.w};
        ushort4 h4, l4;
        unsigned short h[4], l[4];
        #pragma unroll
        for (int i = 0; i < 4; ++i) {
            h[i] = bf16_rne(xs[i]);
            float rem = xs[i] - bf16_to_f(h[i]);
            l[i] = bf16_rne(rem);
        }
        h4.x = h[0]; h4.y = h[1]; h4.z = h[2]; h4.w = h[3];
        l4.x = l[0]; l4.y = l[1]; l4.z = l[2]; l4.w = l[3];
        *reinterpret_cast<ushort4*>(&w1hi[(size_t)f * 4]) = h4;
        *reinterpret_cast<ushort4*>(&w1lo[(size_t)f * 4]) = l4;
    } else {
        for (int c = threadIdx.x; c < DIM; c += 256) {
            float s = 0.f;
            #pragma unroll
            for (int e = 0; e < NSH; ++e) s += shared_w[e * DIM + c];
            shsum[c] = s;
        }
    }
}

// ---------------- kernel A: GEMM + partial logits ----------------
// Grid: 250 row-blocks x 4 col-blocks = 1000 blocks, 256 thr = 4 waves.
// Block: 64 rows x 128 cols. Wave wv: rgrp=wv>>1 (rows rgrp*32+..),
// cgrp=wv&1 (cols cgrp*64+..): 32r x 64c, acc[2 rt][4 ct], 24 MFMA from
// 8 ds_read_b128 (B only).
// A path: NO LDS. Lane (l15,lg) loads its fragment G[row][t*32+lg*8..+8)
// directly global->regs (2 float4), prefetch distance 1 (counted vmcnt),
// converts to hi/lo bf16 in-reg AFTER compute (VALU overlaps MFMA pipe).
// LDS: B dbuf only, 2 x 16 KB = 32 KB -> 4 blocks/CU (VGPR-capped), with
// real inter-block stagger (the thing rounds 2-8 never had).
// Per-iter in-flight: A(t+1) x4 issued FIRST (oldest), B(t+1) x4 second.
// WAITVM(4) -> A landed (B flying, covered by convert); WAITVM(0) -> B
// landed; BAR. No ds_writes anywhere -> no lgkm drain at the barrier.
// BIT-EXACT logit invariants (rounds 4/6/7/8): same bf16 values (same
// bf16_rne on same G elements), same fragment contents, same per-acc pass
// order (hh,lh,hl), ct/k ascending, same 64-col fmaf chain + width-16
// butterfly, w8 = colblk*2+cgrp, finalize sums w8=0..7.
__global__ __launch_bounds__(256, 4)
void gemm_logits(const float* __restrict__ G,
                 const unsigned short* __restrict__ w1hi,
                 const unsigned short* __restrict__ w1lo,
                 const float* __restrict__ W2,
                 float* __restrict__ plogG)
{
    __shared__ unsigned short smem[16384];   // 32768 B: buf = 8192 shorts (Bh 4096, Bl 4096)

    const int tid  = threadIdx.x;
    const int lane = tid & 63;
    const int wv   = tid >> 6;          // 0..3
    const int l15  = lane & 15;
    const int lg   = lane >> 4;         // 0..3
    const int rgrp = wv >> 1;           // 0..1
    const int cgrp = wv & 1;            // 0..1
    const int bx     = blockIdx.x;
    const int colblk = bx & 3;
    const int row0   = (bx >> 2) * TMA;
    const int cb     = colblk * NCB;

    // ---- B staging streams: per thread 2 hi + 2 lo 16B chunks ----
    const unsigned short* bsrc_hi[2];
    int bdst[2];
    #pragma unroll
    for (int r = 0; r < 2; ++r) {
        int f  = r * 256 + tid;          // chunk id 0..511
        int n  = f >> 2;                 // local col 0..127
        int js = (f & 3) ^ ((n >> 1) & 3);   // source pre-swizzle (both-sides)
        bsrc_hi[r] = w1hi + (size_t)(cb + n) * DIM + js * 8;
        bdst[r]    = f * 8;              // shorts within Bh region
    }
    const ptrdiff_t dHL = w1lo - w1hi;   // uniform hi->lo offset (SGPR)

    // ---- A row pointers (fragment = 8 contiguous floats) ----
    const float* gpA[2];
    #pragma unroll
    for (int rt = 0; rt < 2; ++rt)
        gpA[rt] = &G[(size_t)(row0 + rgrp * 32 + rt * 16 + l15) * DIM + lg * 8];

    // ---- B fragment LDS offsets (shorts) ----
    int boff[4];
    #pragma unroll
    for (int ct = 0; ct < 4; ++ct) {
        int n = cgrp * 64 + ct * 16 + l15;
        boff[ct] = n * 32 + (lg ^ ((n >> 1) & 3)) * 8;
    }

    f32x4 acc[2][4];
    #pragma unroll
    for (int rt = 0; rt < 2; ++rt)
        #pragma unroll
        for (int ct = 0; ct < 4; ++ct) acc[rt][ct] = (f32x4)0.f;

    float4 ga[2][2];                    // raw A floats for tile t+1
    bf16x8 ah[2], al[2];                // current A fragments

    auto loadA = [&](int t) {           // 4 global_load_dwordx4
        #pragma unroll
        for (int rt = 0; rt < 2; ++rt) {
            ga[rt][0] = *reinterpret_cast<const float4*>(gpA[rt] + t * BK);
            ga[rt][1] = *reinterpret_cast<const float4*>(gpA[rt] + t * BK + 4);
        }
    };
    auto stageB = [&](int t, int buf) { // 4 gload_lds
        unsigned short* bb = smem + buf * 8192;
        #pragma unroll
        for (int r = 0; r < 2; ++r)
            __builtin_amdgcn_global_load_lds(
                (const __attribute__((address_space(1))) void*)(bsrc_hi[r] + t * BK),
                (__attribute__((address_space(3))) void*)(bb + bdst[r]), 16, 0, 0);
        #pragma unroll
        for (int r = 0; r < 2; ++r)
            __builtin_amdgcn_global_load_lds(
                (const __attribute__((address_space(1))) void*)(bsrc_hi[r] + dHL + t * BK),
                (__attribute__((address_space(3))) void*)(bb + 4096 + bdst[r]), 16, 0, 0);
    };
    auto convertA = [&]() {             // regs -> hi/lo bf16 frags (same bf16_rne)
        #pragma unroll
        for (int rt = 0; rt < 2; ++rt) {
            float xs[8] = {ga[rt][0].x, ga[rt][0].y, ga[rt][0].z, ga[rt][0].w,
                           ga[rt][1].x, ga[rt][1].y, ga[rt][1].z, ga[rt][1].w};
            unsigned short h[8], l[8];
            #pragma unroll
            for (int i = 0; i < 8; ++i) {
                h[i] = bf16_rne(xs[i]);
                l[i] = bf16_rne(xs[i] - bf16_to_f(h[i]));
            }
            ah[rt] = (bf16x8){(short)h[0], (short)h[1], (short)h[2], (short)h[3],
                              (short)h[4], (short)h[5], (short)h[6], (short)h[7]};
            al[rt] = (bf16x8){(short)l[0], (short)l[1], (short)l[2], (short)l[3],
                              (short)l[4], (short)l[5], (short)l[6], (short)l[7]};
        }
    };
    auto computeTile = [&](int buf) {
        const unsigned short* base = smem + buf * 8192;
        bf16x8 bh[4], bl[4];
        #pragma unroll
        for (int ct = 0; ct < 4; ++ct) {
            bh[ct] = *reinterpret_cast<const bf16x8*>(&base[boff[ct]]);
            bl[ct] = *reinterpret_cast<const bf16x8*>(&base[4096 + boff[ct]]);
        }
        __builtin_amdgcn_s_setprio(1);
        // per-acc pass order (hh, lh, hl) == rounds 4/6/7/8 (bit-exact)
        #pragma unroll
        for (int ct = 0; ct < 4; ++ct)
            #pragma unroll
            for (int rt = 0; rt < 2; ++rt)
                acc[rt][ct] = __builtin_amdgcn_mfma_f32_16x16x32_bf16(ah[rt], bh[ct], acc[rt][ct], 0, 0, 0);
        #pragma unroll
        for (int ct = 0; ct < 4; ++ct)
            #pragma unroll
            for (int rt = 0; rt < 2; ++rt)
                acc[rt][ct] = __builtin_amdgcn_mfma_f32_16x16x32_bf16(al[rt], bh[ct], acc[rt][ct], 0, 0, 0);
        #pragma unroll
        for (int ct = 0; ct < 4; ++ct)
            #pragma unroll
            for (int rt = 0; rt < 2; ++rt)
                acc[rt][ct] = __builtin_amdgcn_mfma_f32_16x16x32_bf16(ah[rt], bl[ct], acc[rt][ct], 0, 0, 0);
        __builtin_amdgcn_s_setprio(0);
    };

    // ---- prologue: A(0) (oldest), B(0) ----
    loadA(0);  SB;
    stageB(0, 0);  SB;
    WAITVM(4);                  // A(0) landed
    convertA();
    WAITVM(0);                  // B(0) landed
    BAR;

    // ---- steady loop t = 0..NT-2 ----
    for (int t = 0; t < NT - 1; ++t) {
        loadA(t + 1);  SB;                  // +4 (oldest of this iter)
        stageB(t + 1, (t & 1) ^ 1);  SB;    // +4 -> 8
        computeTile(t & 1);
        WAITVM(4);                  // A(t+1) landed; B(t+1) still flying
        convertA();
        WAITVM(0);                  // B(t+1) landed
        BAR;
    }

    // ---- tail t = NT-1 ----
    computeTile((NT - 1) & 1);

    // ---- ReLU ----
    #pragma unroll
    for (int rt = 0; rt < 2; ++rt)
        #pragma unroll
        for (int ct = 0; ct < 4; ++ct)
            #pragma unroll
            for (int j = 0; j < 4; ++j)
                acc[rt][ct][j] = fmaxf(acc[rt][ct][j], 0.f);

    // ---- per-wave 64-col logit partial (bit-exact tree) ----
    const int w8 = colblk * 2 + cgrp;   // 64-col group index 0..7
    #pragma unroll
    for (int e = 0; e < NEXP; ++e) {
        float w2v[4];
        #pragma unroll
        for (int ct = 0; ct < 4; ++ct)
            w2v[ct] = W2[(size_t)e * DIM + cb + cgrp * 64 + ct * 16 + l15];
        #pragma unroll
        for (int rt = 0; rt < 2; ++rt) {
            #pragma unroll
            for (int j = 0; j < 4; ++j) {
                float s = 0.f;
                #pragma unroll
                for (int ct = 0; ct < 4; ++ct)
                    s = fmaf(acc[rt][ct][j], w2v[ct], s);
                s += __shfl_xor(s, 1, 16);
                s += __shfl_xor(s, 2, 16);
                s += __shfl_xor(s, 4, 16);
                s += __shfl_xor(s, 8, 16);
                if (l15 == 0) {
                    int grow = row0 + rgrp * 32 + rt * 16 + lg * 4 + j;
                    plogG[((size_t)grow * 8 + w8) * NEXP + e] = s;
                }
            }
        }
    }
}

// ---------------- kernel B: reduce 8 partials + softmax/top-5 + output -----
__global__ __launch_bounds__(256)
void finalize(const float* __restrict__ plogG, const float* __restrict__ value,
              const float* __restrict__ shsum, const float* __restrict__ routing_w,
              float* __restrict__ out)
{
    __shared__ float swls[TMF * NEXP];
    const int tid  = threadIdx.x;
    const int row0 = blockIdx.x * TMF;

    if (tid < TMF) {
        const float* pr = &plogG[(size_t)(row0 + tid) * 8 * NEXP];
        float lgt[NEXP];
        #pragma unroll
        for (int e = 0; e < NEXP; ++e) lgt[e] = 0.f;
        #pragma unroll
        for (int w = 0; w < 8; ++w)        // sequential w-order (bit-exact)
            #pragma unroll
            for (int e = 0; e < NEXP; ++e)
                lgt[e] += pr[w * NEXP + e];

        float mx = lgt[0];
        #pragma unroll
        for (int e = 1; e < NEXP; ++e) mx = fmaxf(mx, lgt[e]);
        float p[NEXP], se = 0.f;
        #pragma unroll
        for (int e = 0; e < NEXP; ++e) { p[e] = expf(lgt[e] - mx); se += p[e]; }
        float inv = 1.f / se;
        #pragma unroll
        for (int e = 0; e < NEXP; ++e) p[e] *= inv;
        unsigned used = 0;
        #pragma unroll
        for (int t = 0; t < KTOP; ++t) {
            float bv = -1.f; int bi = 0;
            #pragma unroll
            for (int e = 0; e < NEXP; ++e) {
                bool better = (((used >> e) & 1u) == 0u) && (p[e] > bv);
                bv = better ? p[e] : bv;
                bi = better ? e : bi;
            }
            used |= 1u << bi;
        }
        #pragma unroll
        for (int e = 0; e < NEXP; ++e)
            swls[tid * NEXP + e] = ((used >> e) & 1u) ? p[e] : 0.f;
    }
    __syncthreads();

    const int c4 = (tid & 127) * 4;
    const int rh = tid >> 7;
    float4 sh4 = *reinterpret_cast<const float4*>(&shsum[c4]);
    float4 rw4[NEXP];
    #pragma unroll
    for (int e = 0; e < NEXP; ++e)
        rw4[e] = *reinterpret_cast<const float4*>(&routing_w[(size_t)e * DIM + c4]);
    #pragma unroll
    for (int r = 0; r < 16; ++r) {
        int row = rh * 16 + r;
        float val = value[row0 + row];
        float4 o = sh4;
        #pragma unroll
        for (int e = 0; e < NEXP; ++e) {
            float wgt = swls[row * NEXP + e];
            o.x = fmaf(wgt, rw4[e].x, o.x);
            o.y = fmaf(wgt, rw4[e].y, o.y);
            o.z = fmaf(wgt, rw4[e].z, o.z);
            o.w = fmaf(wgt, rw4[e].w, o.w);
        }
        o.x *= val; o.y *= val; o.z *= val; o.w *= val;
        *reinterpret_cast<float4*>(&out[(size_t)(row0 + row) * DIM + c4]) = o;
    }
}

extern "C" void kernel_launch(void* const* d_in, const int* in_sizes, int n_in,
                              void* d_out, int out_size, void* d_ws, size_t ws_size,
                              hipStream_t stream) {
    const float* G         = (const float*)d_in[0];
    const float* value     = (const float*)d_in[1];
    const float* shared_w  = (const float*)d_in[2];
    const float* routing_w = (const float*)d_in[3];
    const float* W1        = (const float*)d_in[4];
    const float* W2        = (const float*)d_in[5];
    float* out             = (float*)d_out;

    unsigned short* w1hi = (unsigned short*)d_ws;                        // 512 KB
    unsigned short* w1lo = (unsigned short*)((char*)d_ws + 524288);      // 512 KB
    float*          shs  = (float*)((char*)d_ws + 1048576);              // 2 KB
    float*          plg  = (float*)((char*)d_ws + 1056768);              // 5.12 MB [M][8][10]

    prep_kernel<<<257, 256, 0, stream>>>(W1, shared_w, w1hi, w1lo, shs);
    gemm_logits<<<(M_ROWS / TMA) * 4, 256, 0, stream>>>(G, w1hi, w1lo, W2, plg);
    finalize<<<M_ROWS / TMF, 256, 0, stream>>>(plg, value, shs, routing_w, out);
}

// Round 10
// 78.992 us; speedup vs baseline: 1.0563x; 1.0563x over previous
//
#include <hip/hip_runtime.h>

constexpr int M_ROWS = 16000;   // B*T
constexpr int DIM    = 512;
constexpr int NEXP   = 10;
constexpr int NSH    = 5;
constexpr int KTOP   = 5;

constexpr int TMA = 64;         // rows per block
constexpr int BK  = 32;         // k-step
constexpr int NT  = DIM / BK;   // 16

typedef __attribute__((ext_vector_type(8))) short  bf16x8;
typedef __attribute__((ext_vector_type(4))) float  f32x4;

#define SB __builtin_amdgcn_sched_barrier(0)

__device__ inline unsigned short bf16_rne(float x) {
    unsigned u = __float_as_uint(x);
    u += 0x7fffu + ((u >> 16) & 1u);
    return (unsigned short)(u >> 16);
}
__device__ inline float bf16_to_f(unsigned short h) {
    return __uint_as_float(((unsigned)h) << 16);
}

// ---------------- prep: W1 -> (hi,lo) bf16 [N][K]; shsum = sum_s shared_w ----
__global__ __launch_bounds__(256)
void prep_kernel(const float* __restrict__ W1, const float* __restrict__ shared_w,
                 unsigned short* __restrict__ w1hi, unsigned short* __restrict__ w1lo,
                 float* __restrict__ shsum)
{
    int b = blockIdx.x;
    if (b < 256) {
        int f = b * 256 + threadIdx.x;
        float4 v = *reinterpret_cast<const float4*>(&W1[(size_t)f * 4]);
        float xs[4] = {v.x, v.y, v.z, v.w};
        ushort4 h4, l4;
        unsigned short h[4], l[4];
        #pragma unroll
        for (int i = 0; i < 4; ++i) {
            h[i] = bf16_rne(xs[i]);
            float rem = xs[i] - bf16_to_f(h[i]);
            l[i] = bf16_rne(rem);
        }
        h4.x = h[0]; h4.y = h[1]; h4.z = h[2]; h4.w = h[3];
        l4.x = l[0]; l4.y = l[1]; l4.z = l[2]; l4.w = l[3];
        *reinterpret_cast<ushort4*>(&w1hi[(size_t)f * 4]) = h4;
        *reinterpret_cast<ushort4*>(&w1lo[(size_t)f * 4]) = l4;
    } else {
        for (int c = threadIdx.x; c < DIM; c += 256) {
            float s = 0.f;
            #pragma unroll
            for (int e = 0; e < NSH; ++e) s += shared_w[e * DIM + c];
            shsum[c] = s;
        }
    }
}

// ---------------- fused GEMM + logits + softmax/top5 + output ----------------
// Grid: 250 blocks (64 rows each), 512 thr = 8 waves. Wave wv owns cols
// [wv*64, wv*64+64) x ALL 64 rows: acc[4 rt][4 ct], 48 MFMA / 8 A-ds_reads
// per k-step. A (G rows, hi/lo bf16) parked in 128 KB static LDS, staged
// ONCE per block (reg-stage + R7-verified swizzle: conflict-free). B (w1hi/lo)
// streamed global->reg per wave from L2, register-double-buffered. NO barriers
// in the k-loop, no in-loop LDS writes, no in-loop converts.
// LDS (shorts): Ahi[16][64][32] @ 0, Alo @ 32768. After k-loop (barrier),
// overlay plog[64][8][10] f32 + swls[64][10].
// BIT-EXACT invariants (rounds 4/6/7/8): same bf16_rne on same G/W1 elements,
// same fragment<->(row,k,col) mapping, per-acc pass order (hh,lh,hl) at t
// ascending, 64-col fmaf chain ct=0..3 + width-16 butterfly (xor 1,2,4,8),
// cross-group sum w=0..7 sequential, same softmax/top5/epilogue.
__global__ __launch_bounds__(512, 2)
void moe_fused(const float* __restrict__ G, const float* __restrict__ value,
               const float* __restrict__ routing_w, const float* __restrict__ W2,
               const unsigned short* __restrict__ w1hi,
               const unsigned short* __restrict__ w1lo,
               const float* __restrict__ shsum, float* __restrict__ out)
{
    __shared__ unsigned short smem[65536];   // 131072 B

    const int tid  = threadIdx.x;
    const int lane = tid & 63;
    const int wv   = tid >> 6;          // 0..7 = 64-col group (== w8)
    const int l15  = lane & 15;
    const int lg   = lane >> 4;         // 0..3
    const int row0 = blockIdx.x * TMA;
    const int cbw  = wv * 64;           // wave's global col base

    // ---- A staging mapping (R7-verified swizzle) ----
    const int arow = tid >> 3;          // 0..63
    const int aq   = tid & 7;           // 0..7
    const int acol = ((aq >> 1) ^ ((arow >> 1) & 3)) * 8 + (aq & 1) * 4;
    const float* gpr = &G[(size_t)(row0 + arow) * DIM + aq * 4];

    // ---- B stream pointers (per ct, 16B fragment each k-step) ----
    const unsigned short* bsrc[4];
    #pragma unroll
    for (int ct = 0; ct < 4; ++ct)
        bsrc[ct] = w1hi + (size_t)(cbw + ct * 16 + l15) * DIM + lg * 8;
    const ptrdiff_t dHL = w1lo - w1hi;

    // ---- A fragment read offsets (shorts within a kstep tile) ----
    int aoff[4];
    #pragma unroll
    for (int rt = 0; rt < 4; ++rt) {
        int r_ = rt * 16 + l15;
        aoff[rt] = r_ * 32 + (lg ^ ((r_ >> 1) & 3)) * 8;
    }

    f32x4 acc[4][4];
    #pragma unroll
    for (int rt = 0; rt < 4; ++rt)
        #pragma unroll
        for (int ct = 0; ct < 4; ++ct) acc[rt][ct] = (f32x4)0.f;

    // ---- free prefetch: B(0) into bank 0 (drains during A-stage) ----
    bf16x8 bh[2][4], bl[2][4];
    #pragma unroll
    for (int ct = 0; ct < 4; ++ct) {
        bh[0][ct] = *reinterpret_cast<const bf16x8*>(bsrc[ct]);
        bl[0][ct] = *reinterpret_cast<const bf16x8*>(bsrc[ct] + dHL);
    }
    SB;

    // ---- stage A once: G fp32 -> hi/lo bf16 -> swizzled LDS ----
    #pragma unroll 4
    for (int t = 0; t < NT; ++t) {
        float4 g4 = *reinterpret_cast<const float4*>(gpr + t * BK);
        float xs[4] = {g4.x, g4.y, g4.z, g4.w};
        unsigned short h[4], l[4];
        #pragma unroll
        for (int i = 0; i < 4; ++i) {
            h[i] = bf16_rne(xs[i]);
            l[i] = bf16_rne(xs[i] - bf16_to_f(h[i]));
        }
        ushort4 h4, l4;
        h4.x = h[0]; h4.y = h[1]; h4.z = h[2]; h4.w = h[3];
        l4.x = l[0]; l4.y = l[1]; l4.z = l[2]; l4.w = l[3];
        *reinterpret_cast<ushort4*>(&smem[t * 2048 + arow * 32 + acol])         = h4;
        *reinterpret_cast<ushort4*>(&smem[32768 + t * 2048 + arow * 32 + acol]) = l4;
    }
    __syncthreads();

    // ---- barrier-free k-loop, reg-dbuf B, prefetch distance 1 ----
    #pragma unroll 2
    for (int t = 0; t < NT; ++t) {
        const int cur = t & 1;
        const int nxt = cur ^ 1;
        if (t + 1 < NT) {
            #pragma unroll
            for (int ct = 0; ct < 4; ++ct) {
                bh[nxt][ct] = *reinterpret_cast<const bf16x8*>(bsrc[ct] + (t + 1) * BK);
                bl[nxt][ct] = *reinterpret_cast<const bf16x8*>(bsrc[ct] + dHL + (t + 1) * BK);
            }
        }
        SB;
        bf16x8 ah[4], al[4];
        #pragma unroll
        for (int rt = 0; rt < 4; ++rt) {
            ah[rt] = *reinterpret_cast<const bf16x8*>(&smem[t * 2048 + aoff[rt]]);
            al[rt] = *reinterpret_cast<const bf16x8*>(&smem[32768 + t * 2048 + aoff[rt]]);
        }
        __builtin_amdgcn_s_setprio(1);
        // per-acc pass order (hh, lh, hl) == rounds 4/6/7/8 (bit-exact)
        #pragma unroll
        for (int ct = 0; ct < 4; ++ct)
            #pragma unroll
            for (int rt = 0; rt < 4; ++rt)
                acc[rt][ct] = __builtin_amdgcn_mfma_f32_16x16x32_bf16(ah[rt], bh[cur][ct], acc[rt][ct], 0, 0, 0);
        #pragma unroll
        for (int ct = 0; ct < 4; ++ct)
            #pragma unroll
            for (int rt = 0; rt < 4; ++rt)
                acc[rt][ct] = __builtin_amdgcn_mfma_f32_16x16x32_bf16(al[rt], bh[cur][ct], acc[rt][ct], 0, 0, 0);
        #pragma unroll
        for (int ct = 0; ct < 4; ++ct)
            #pragma unroll
            for (int rt = 0; rt < 4; ++rt)
                acc[rt][ct] = __builtin_amdgcn_mfma_f32_16x16x32_bf16(ah[rt], bl[cur][ct], acc[rt][ct], 0, 0, 0);
        __builtin_amdgcn_s_setprio(0);
    }

    __syncthreads();    // all waves done reading A-LDS before overlay

    // ---- ReLU ----
    #pragma unroll
    for (int rt = 0; rt < 4; ++rt)
        #pragma unroll
        for (int ct = 0; ct < 4; ++ct)
            #pragma unroll
            for (int j = 0; j < 4; ++j)
                acc[rt][ct][j] = fmaxf(acc[rt][ct][j], 0.f);

    // ---- per-wave 64-col logit partials -> LDS (bit-exact tree) ----
    float* plog = reinterpret_cast<float*>(smem);        // [64][8][10]
    float* swls = plog + TMA * 8 * NEXP;                 // [64][10]

    #pragma unroll
    for (int e = 0; e < NEXP; ++e) {
        float w2v[4];
        #pragma unroll
        for (int ct = 0; ct < 4; ++ct)
            w2v[ct] = W2[(size_t)e * DIM + cbw + ct * 16 + l15];
        #pragma unroll
        for (int rt = 0; rt < 4; ++rt) {
            #pragma unroll
            for (int j = 0; j < 4; ++j) {
                float s = 0.f;
                #pragma unroll
                for (int ct = 0; ct < 4; ++ct)
                    s = fmaf(acc[rt][ct][j], w2v[ct], s);
                s += __shfl_xor(s, 1, 16);
                s += __shfl_xor(s, 2, 16);
                s += __shfl_xor(s, 4, 16);
                s += __shfl_xor(s, 8, 16);
                if (l15 == 0) {
                    int rloc = rt * 16 + lg * 4 + j;
                    plog[(rloc * 8 + wv) * NEXP + e] = s;
                }
            }
        }
    }
    __syncthreads();

    // ---- reduce 8 partials + softmax + top-5 (one thread per row) ----
    if (tid < TMA) {
        const float* pr = &plog[tid * 8 * NEXP];
        float lgt[NEXP];
        #pragma unroll
        for (int e = 0; e < NEXP; ++e) lgt[e] = 0.f;
        #pragma unroll
        for (int w = 0; w < 8; ++w)        // sequential w-order (bit-exact)
            #pragma unroll
            for (int e = 0; e < NEXP; ++e)
                lgt[e] += pr[w * NEXP + e];

        float mx = lgt[0];
        #pragma unroll
        for (int e = 1; e < NEXP; ++e) mx = fmaxf(mx, lgt[e]);
        float p[NEXP], se = 0.f;
        #pragma unroll
        for (int e = 0; e < NEXP; ++e) { p[e] = expf(lgt[e] - mx); se += p[e]; }
        float inv = 1.f / se;
        #pragma unroll
        for (int e = 0; e < NEXP; ++e) p[e] *= inv;
        unsigned used = 0;
        #pragma unroll
        for (int t = 0; t < KTOP; ++t) {
            float bv = -1.f; int bi = 0;
            #pragma unroll
            for (int e = 0; e < NEXP; ++e) {
                bool better = (((used >> e) & 1u) == 0u) && (p[e] > bv);
                bv = better ? p[e] : bv;
                bi = better ? e : bi;
            }
            used |= 1u << bi;
        }
        #pragma unroll
        for (int e = 0; e < NEXP; ++e)
            swls[tid * NEXP + e] = ((used >> e) & 1u) ? p[e] : 0.f;
    }
    __syncthreads();

    // ---- output epilogue: 64 rows x 512 cols ----
    const int c4   = (tid & 127) * 4;
    const int rblk = tid >> 7;           // 0..3 -> rows rblk*16..+15
    float4 sh4 = *reinterpret_cast<const float4*>(&shsum[c4]);
    float4 rw4[NEXP];
    #pragma unroll
    for (int e = 0; e < NEXP; ++e)
        rw4[e] = *reinterpret_cast<const float4*>(&routing_w[(size_t)e * DIM + c4]);
    #pragma unroll
    for (int r = 0; r < 16; ++r) {
        int row = rblk * 16 + r;
        float val = value[row0 + row];
        float4 o = sh4;
        #pragma unroll
        for (int e = 0; e < NEXP; ++e) {
            float wgt = swls[row * NEXP + e];
            o.x = fmaf(wgt, rw4[e].x, o.x);
            o.y = fmaf(wgt, rw4[e].y, o.y);
            o.z = fmaf(wgt, rw4[e].z, o.z);
            o.w = fmaf(wgt, rw4[e].w, o.w);
        }
        o.x *= val; o.y *= val; o.z *= val; o.w *= val;
        *reinterpret_cast<float4*>(&out[(size_t)(row0 + row) * DIM + c4]) = o;
    }
}

extern "C" void kernel_launch(void* const* d_in, const int* in_sizes, int n_in,
                              void* d_out, int out_size, void* d_ws, size_t ws_size,
                              hipStream_t stream) {
    const float* G         = (const float*)d_in[0];
    const float* value     = (const float*)d_in[1];
    const float* shared_w  = (const float*)d_in[2];
    const float* routing_w = (const float*)d_in[3];
    const float* W1        = (const float*)d_in[4];
    const float* W2        = (const float*)d_in[5];
    float* out             = (float*)d_out;

    unsigned short* w1hi = (unsigned short*)d_ws;                        // 512 KB
    unsigned short* w1lo = (unsigned short*)((char*)d_ws + 524288);      // 512 KB
    float*          shs  = (float*)((char*)d_ws + 1048576);              // 2 KB

    prep_kernel<<<257, 256, 0, stream>>>(W1, shared_w, w1hi, w1lo, shs);
    moe_fused<<<M_ROWS / TMA, 512, 0, stream>>>(G, value, routing_w, W2,
                                                w1hi, w1lo, shs, out);
}